// Round 4
// baseline (270.659 us; speedup 1.0000x reference)
//
#include <hip/hip_runtime.h>
#include <math.h>

#define NN 8
#define CC 64
#define HH 256
#define WW 256
#define GG 8
#define K2 9
#define OC 72          // G*k2
#define BN_EPS 1e-5f

typedef float vfloat4 __attribute__((ext_vector_type(4)));  // native vector: ok for nontemporal builtin

// ---------------- Kernel 1: adaptive avg pool (N,C,H,W) -> pooled[N*C] ----------
// 1024 threads/block; 512 blocks -> 2 blocks/CU = 32 waves/CU (full occupancy).
__global__ __launch_bounds__(1024) void pool_kernel(const float* __restrict__ x,
                                                    float* __restrict__ pooled) {
    int nc = blockIdx.x;                       // 0 .. N*C-1
    const float4* p4 = (const float4*)(x + (size_t)nc * (HH * WW));
    float s = 0.f;
#pragma unroll 4
    for (int i = threadIdx.x; i < (HH * WW) / 4; i += 1024) {
        float4 v = p4[i];
        s += (v.x + v.y) + (v.z + v.w);
    }
    for (int off = 32; off > 0; off >>= 1) s += __shfl_down(s, off, 64);
    __shared__ float smem[16];
    int lane = threadIdx.x & 63, wid = threadIdx.x >> 6;
    if (lane == 0) smem[wid] = s;
    __syncthreads();
    if (threadIdx.x < 16) {
        float t = smem[threadIdx.x];
        for (int off = 8; off > 0; off >>= 1) t += __shfl_down(t, off, 64);
        if (threadIdx.x == 0) pooled[nc] = t * (1.0f / (HH * WW));
    }
}

// ---------------- Main: fused lf + dynamic 3x3 conv + affine combine ------------
// One wave handles 8 consecutive rows: loads 10 rows (float4/lane), computes 8.
// Block = 4 waves = 32 rows. 8 blocks per (n,c) image. Grid = N*C*8 = 4096.
// The per-(n,g) 3x3 filter (1x1conv+BN+tanh on pooled) is computed per-wave via
// shuffle-reduce dot products -- removes the separate lf dispatch.
__global__ __launch_bounds__(256) void main_kernel(const float* __restrict__ x,
                                                   const float* __restrict__ pooled,
                                                   const float* __restrict__ conv_w,
                                                   const float* __restrict__ gamma,
                                                   const float* __restrict__ beta,
                                                   const float* __restrict__ mean,
                                                   const float* __restrict__ var,
                                                   const float* __restrict__ lamb_l,
                                                   const float* __restrict__ lamb_h,
                                                   const float* __restrict__ ia,
                                                   float* __restrict__ out) {
    const int wid  = threadIdx.x >> 6;          // wave 0..3
    const int lane = threadIdx.x & 63;
    const int nc   = blockIdx.x >> 3;           // 8 blocks per image
    const int r0   = ((blockIdx.x & 7) << 5) + (wid << 3);  // first of 8 output rows
    const int c    = nc & (CC - 1);
    const int n    = nc >> 6;
    const int g    = c >> 3;                    // C/G = 8

    // ---- fused lf: 9 dot products of length 64 via wave shuffle-reduce ----
    const float pc = pooled[n * CC + lane];     // lane <-> input channel (CC==64)
    float wgt[K2];
#pragma unroll
    for (int q = 0; q < K2; ++q) {
        const int oc = g * K2 + q;
        float part = pc * conv_w[oc * CC + lane];
        for (int off = 32; off > 0; off >>= 1) part += __shfl_down(part, off, 64);
        const float dot = __shfl(part, 0, 64);
        const float inv = gamma[oc] * rsqrtf(var[oc] + BN_EPS);
        wgt[q] = tanhf((dot - mean[oc]) * inv + beta[oc]);
    }
    const float w00 = wgt[0], w01 = wgt[1], w02 = wgt[2];
    const float w10 = wgt[3], w11 = wgt[4], w12 = wgt[5];
    const float w20 = wgt[6], w21 = wgt[7], w22 = wgt[8];

    const float ll    = lamb_l[c];
    const float lh1   = lamb_h[c] + 1.0f;
    const float iav   = ia[c];
    const float scale = iav + 1.0f;
    const float bias  = -iav * pooled[nc];

    const float* base = x + (size_t)nc * (HH * WW);

    float4 v[10];
    float  L[10], R[10];
#pragma unroll
    for (int i = 0; i < 10; ++i) {
        int r = r0 - 1 + i;
        r = (r < 0) ? 1 : ((r > HH - 1) ? HH - 2 : r);   // reflection pad
        v[i] = ((const float4*)(base + r * WW))[lane];
    }
#pragma unroll
    for (int i = 0; i < 10; ++i) {
        L[i] = __shfl_up(v[i].w, 1, 64);   if (lane == 0)  L[i] = v[i].y;
        R[i] = __shfl_down(v[i].x, 1, 64); if (lane == 63) R[i] = v[i].z;
    }

    float* outbase = out + (size_t)nc * (HH * WW);
#pragma unroll
    for (int j = 0; j < 8; ++j) {
        const float t[6] = {L[j],   v[j].x,   v[j].y,   v[j].z,   v[j].w,   R[j]};
        const float m[6] = {L[j+1], v[j+1].x, v[j+1].y, v[j+1].z, v[j+1].w, R[j+1]};
        const float b[6] = {L[j+2], v[j+2].x, v[j+2].y, v[j+2].z, v[j+2].w, R[j+2]};
        vfloat4 o;
#pragma unroll
        for (int k = 0; k < 4; ++k) {
            float acc = w00 * t[k] + w01 * t[k + 1] + w02 * t[k + 2]
                      + w10 * m[k] + w11 * m[k + 1] + w12 * m[k + 2]
                      + w20 * b[k] + w21 * b[k + 1] + w22 * b[k + 2];
            o[k] = ll * (scale * acc + bias) + lh1 * m[k + 1];
        }
        // out is write-once, never re-read: non-temporal keeps x resident in L3
        __builtin_nontemporal_store(o, (vfloat4*)(outbase + (size_t)(r0 + j) * WW) + lane);
    }
}

extern "C" void kernel_launch(void* const* d_in, const int* in_sizes, int n_in,
                              void* d_out, int out_size, void* d_ws, size_t ws_size,
                              hipStream_t stream) {
    const float* x      = (const float*)d_in[0];
    const float* conv_w = (const float*)d_in[1];
    const float* gamma  = (const float*)d_in[2];
    const float* beta   = (const float*)d_in[3];
    const float* mean   = (const float*)d_in[4];
    const float* var    = (const float*)d_in[5];
    const float* lamb_l = (const float*)d_in[6];
    const float* lamb_h = (const float*)d_in[7];
    const float* ia     = (const float*)d_in[8];
    float* out = (float*)d_out;

    float* pooled = (float*)d_ws;              // N*C = 512 floats

    pool_kernel<<<NN * CC, 1024, 0, stream>>>(x, pooled);
    main_kernel<<<NN * CC * (HH / 32), 256, 0, stream>>>(x, pooled, conv_w, gamma, beta,
                                                         mean, var, lamb_l, lamb_h, ia, out);
}